// Round 4
// baseline (571.948 us; speedup 1.0000x reference)
//
#include <hip/hip_runtime.h>
#include <hip/hip_bf16.h>
#include <cstdint>
#include <cstddef>

// ---------------------------------------------------------------------------
// CausalSelfAttention: x[2,4096,768] fp32, W_qkv[768,2304], b_qkv, W_proj[768,768], b_proj
// bf16 MFMA (16x16x32); flash attention, S^T trick, fixed-max softmax,
// 32 Q-rows/wave, register-prefetch pipeline on all staging loops.
// ---------------------------------------------------------------------------

typedef __attribute__((ext_vector_type(8))) short bf16x8;   // 8 bf16 = 4 VGPRs
typedef __attribute__((ext_vector_type(4))) float f32x4;

#define MFMA16(a, b, c) __builtin_amdgcn_mfma_f32_16x16x32_bf16((a), (b), (c), 0, 0, 0)

static constexpr int Bc = 2, Tc = 4096, Dc = 768, Hc = 12, DKc = 64;
static constexpr int BHc = Bc * Hc;      // 24
static constexpr int Mc = Bc * Tc;       // 8192
static constexpr int Nqkv = 3 * Dc;      // 2304

__device__ __forceinline__ float bf2f(unsigned short u) {
    union { unsigned int i; float f; } c;
    c.i = ((unsigned int)u) << 16;
    return c.f;
}
__device__ __forceinline__ unsigned short f2bf(float f) {
    union { float f; unsigned int i; } c; c.f = f;
    unsigned int x = c.i;
    return (unsigned short)((x + 0x7fffu + ((x >> 16) & 1u)) >> 16); // RNE
}
__device__ __forceinline__ unsigned int pkbf(float a, float b) {
    __hip_bfloat162 h = __float22bfloat162_rn(make_float2(a, b));   // v_cvt_pk_bf16_f32
    union { __hip_bfloat162 h; unsigned int u; } c; c.h = h;
    return c.u;
}

// ---------------------------------------------------------------------------
// x fp32 -> bf16, flat copy.
// ---------------------------------------------------------------------------
__global__ __launch_bounds__(256)
void xconv_kernel(const float* __restrict__ X, unsigned short* __restrict__ Xb) {
    size_t i = ((size_t)blockIdx.x * 256 + threadIdx.x) * 8;
    float4 a = *(const float4*)(X + i);
    float4 b = *(const float4*)(X + i + 4);
    uint4 o;
    o.x = pkbf(a.x, a.y); o.y = pkbf(a.z, a.w);
    o.z = pkbf(b.x, b.y); o.w = pkbf(b.z, b.w);
    *(uint4*)(Xb + i) = o;
}

// ---------------------------------------------------------------------------
// W [K][N] fp32 -> WT [N][K] bf16.  grid (K/64, N/64), 256 thr.
// ---------------------------------------------------------------------------
__global__ __launch_bounds__(256)
void wtrans_kernel(const float* __restrict__ W, unsigned short* __restrict__ WT,
                   int K, int N) {
    __shared__ __align__(16) unsigned short tile[64 * 72];
    const int k0 = blockIdx.x * 64;
    const int n0 = blockIdx.y * 64;
    const int tid = threadIdx.x;
#pragma unroll
    for (int it = 0; it < 4; ++it) {
        int s = tid + it * 256;
        int r = s >> 4, g = s & 15;
        float4 v = *(const float4*)(W + (size_t)(k0 + r) * N + n0 + g * 4);
        ushort4 u;
        u.x = f2bf(v.x); u.y = f2bf(v.y); u.z = f2bf(v.z); u.w = f2bf(v.w);
        *(ushort4*)(tile + r * 72 + g * 4) = u;
    }
    __syncthreads();
#pragma unroll
    for (int it = 0; it < 2; ++it) {
        int s = tid + it * 256;
        int n = s >> 3, g = s & 7;
        unsigned int p0 = (unsigned int)tile[(g * 8 + 0) * 72 + n] |
                          ((unsigned int)tile[(g * 8 + 1) * 72 + n] << 16);
        unsigned int p1 = (unsigned int)tile[(g * 8 + 2) * 72 + n] |
                          ((unsigned int)tile[(g * 8 + 3) * 72 + n] << 16);
        unsigned int p2 = (unsigned int)tile[(g * 8 + 4) * 72 + n] |
                          ((unsigned int)tile[(g * 8 + 5) * 72 + n] << 16);
        unsigned int p3 = (unsigned int)tile[(g * 8 + 6) * 72 + n] |
                          ((unsigned int)tile[(g * 8 + 7) * 72 + n] << 16);
        uint4 o; o.x = p0; o.y = p1; o.z = p2; o.w = p3;
        *(uint4*)(WT + (size_t)(n0 + n) * K + k0 + g * 8) = o;
    }
}

// ---------------------------------------------------------------------------
// Vb [bh][T][64] bf16 -> Vt [bh][64][T] bf16. grid (T/64, BH), 256 thr.
// ---------------------------------------------------------------------------
__global__ __launch_bounds__(256)
void vtrans_kernel(const unsigned short* __restrict__ Vb, unsigned short* __restrict__ Vt) {
    __shared__ __align__(16) unsigned short tile[64 * 72];
    const int bh = blockIdx.y;
    const int t0 = blockIdx.x * 64;
    const int tid = threadIdx.x;
    const unsigned short* src = Vb + (size_t)bh * Tc * DKc;
    unsigned short* dst = Vt + (size_t)bh * DKc * Tc;
#pragma unroll
    for (int it = 0; it < 2; ++it) {
        int s = tid + it * 256;
        int r = s >> 3, g = s & 7;
        *(uint4*)(tile + r * 72 + g * 8) =
            *(const uint4*)(src + (size_t)(t0 + r) * DKc + g * 8);
    }
    __syncthreads();
#pragma unroll
    for (int it = 0; it < 2; ++it) {
        int s = tid + it * 256;
        int d = s >> 3, g = s & 7;
        unsigned int p0 = (unsigned int)tile[(g * 8 + 0) * 72 + d] |
                          ((unsigned int)tile[(g * 8 + 1) * 72 + d] << 16);
        unsigned int p1 = (unsigned int)tile[(g * 8 + 2) * 72 + d] |
                          ((unsigned int)tile[(g * 8 + 3) * 72 + d] << 16);
        unsigned int p2 = (unsigned int)tile[(g * 8 + 4) * 72 + d] |
                          ((unsigned int)tile[(g * 8 + 5) * 72 + d] << 16);
        unsigned int p3 = (unsigned int)tile[(g * 8 + 6) * 72 + d] |
                          ((unsigned int)tile[(g * 8 + 7) * 72 + d] << 16);
        uint4 o; o.x = p0; o.y = p1; o.z = p2; o.w = p3;
        *(uint4*)(dst + (size_t)d * Tc + t0 + g * 8) = o;
    }
}

// ---------------------------------------------------------------------------
// QKV GEMM: Xb[8192][768] bf16 x WqT[2304][768] bf16 (+bias) -> Q/K/V [bh][t][dk]
// Q part (and its bias) pre-scaled by 1/8. Register-prefetch pipeline.
// grid (64, 18), 256 thr.
// ---------------------------------------------------------------------------
__global__ __launch_bounds__(256)
void qkv_gemm_kernel(const unsigned short* __restrict__ Xb,
                     const unsigned short* __restrict__ WT,
                     const float* __restrict__ bias,
                     unsigned short* __restrict__ Qb, unsigned short* __restrict__ Kb,
                     unsigned short* __restrict__ Vb) {
    __shared__ __align__(16) unsigned short As[128 * 40];
    __shared__ __align__(16) unsigned short Bs[128 * 40];
    const int tid = threadIdx.x;
    const int wave = tid >> 6, lane = tid & 63;
    const int quad = lane >> 4, l15 = lane & 15;
    const int wr = wave >> 1, wc = wave & 1;
    const int r0 = blockIdx.x * 128, c0 = blockIdx.y * 128;
    const int rr = tid >> 2, gg = tid & 3;   // staging lane map (r = rr + it*64)

    f32x4 acc[4][4];
#pragma unroll
    for (int i = 0; i < 4; ++i)
#pragma unroll
        for (int j = 0; j < 4; ++j) acc[i][j] = (f32x4){0.f, 0.f, 0.f, 0.f};

    uint4 areg[2], breg[2];
#pragma unroll
    for (int it = 0; it < 2; ++it) {
        int r = rr + it * 64;
        areg[it] = *(const uint4*)(Xb + (size_t)(r0 + r) * Dc + gg * 8);
        breg[it] = *(const uint4*)(WT + (size_t)(c0 + r) * Dc + gg * 8);
    }

    for (int k0 = 0; k0 < Dc; k0 += 32) {
#pragma unroll
        for (int it = 0; it < 2; ++it) {
            int r = rr + it * 64;
            *(uint4*)(As + r * 40 + gg * 8) = areg[it];
            *(uint4*)(Bs + r * 40 + gg * 8) = breg[it];
        }
        __syncthreads();
        if (k0 + 32 < Dc) {
#pragma unroll
            for (int it = 0; it < 2; ++it) {
                int r = rr + it * 64;
                areg[it] = *(const uint4*)(Xb + (size_t)(r0 + r) * Dc + k0 + 32 + gg * 8);
                breg[it] = *(const uint4*)(WT + (size_t)(c0 + r) * Dc + k0 + 32 + gg * 8);
            }
        }
        bf16x8 af[4], bfr[4];
#pragma unroll
        for (int mt = 0; mt < 4; ++mt)
            af[mt] = *(const bf16x8*)(As + (wr * 64 + mt * 16 + l15) * 40 + quad * 8);
#pragma unroll
        for (int nt = 0; nt < 4; ++nt)
            bfr[nt] = *(const bf16x8*)(Bs + (wc * 64 + nt * 16 + l15) * 40 + quad * 8);
#pragma unroll
        for (int mt = 0; mt < 4; ++mt)
#pragma unroll
            for (int nt = 0; nt < 4; ++nt)
                acc[mt][nt] = MFMA16(af[mt], bfr[nt], acc[mt][nt]);
        __syncthreads();
    }

    const int part = c0 / Dc;
    unsigned short* dstbuf = (part == 0) ? Qb : ((part == 1) ? Kb : Vb);
    const float scale = (part == 0) ? 0.125f : 1.0f;   // fold 1/sqrt(DK) into Q
    const int cbase = c0 - part * Dc;
    float bv[4];
#pragma unroll
    for (int nt = 0; nt < 4; ++nt) bv[nt] = bias[c0 + wc * 64 + nt * 16 + l15];
#pragma unroll
    for (int mt = 0; mt < 4; ++mt) {
#pragma unroll
        for (int reg = 0; reg < 4; ++reg) {
            int gr = r0 + wr * 64 + mt * 16 + quad * 4 + reg;
            int b = gr >> 12, t = gr & 4095;
#pragma unroll
            for (int nt = 0; nt < 4; ++nt) {
                int cc = cbase + wc * 64 + nt * 16 + l15;
                int h = cc >> 6, dk = cc & 63;
                float v = (acc[mt][nt][reg] + bv[nt]) * scale;
                dstbuf[((size_t)(b * Hc + h) * Tc + t) * DKc + dk] = f2bf(v);
            }
        }
    }
}

// ---------------------------------------------------------------------------
// Flash attention, S^T trick, fixed-max softmax, 32 Q-rows/wave, prefetch.
// grid (T/128, BH), 256 thr; longest blocks launch first.
// Per 64-key tile: prefetched K/V regs -> LDS; sync; issue next tile's global
// loads (latency hidden behind compute); kf/vf frags loaded once, reused by
// both q-groups; P round-trips per-wave LDS; 2 barriers/tile.
// ---------------------------------------------------------------------------
__global__ __launch_bounds__(256)
void attn_kernel(const unsigned short* __restrict__ Qb,
                 const unsigned short* __restrict__ Kb,
                 const unsigned short* __restrict__ Vt,
                 unsigned short* __restrict__ attn) {
    __shared__ __align__(16) unsigned short Ks[64 * 72];
    __shared__ __align__(16) unsigned short Vs[64 * 72];   // [dk][key]
    __shared__ __align__(16) unsigned short Ps[4 * 16 * 72];
    __shared__ float Linv[128];
    const int bh = blockIdx.y;
    const int i0 = (gridDim.x - 1 - blockIdx.x) * 128;     // longest first
    const int tid = threadIdx.x;
    const int wave = tid >> 6, lane = tid & 63;
    const int quad = lane >> 4, l15 = lane & 15;
    const int rr = tid >> 3, gg = tid & 7;                 // staging map (r = rr + it*32)
    const unsigned short* Qp = Qb + (size_t)bh * Tc * DKc;
    const unsigned short* Kp = Kb + (size_t)bh * Tc * DKc;
    const unsigned short* Vp = Vt + (size_t)bh * DKc * Tc;

    // Q fragments for both 16-row groups (already scaled by 1/8 in qkv_gemm)
    bf16x8 qf[2][2];
#pragma unroll
    for (int qg = 0; qg < 2; ++qg)
#pragma unroll
        for (int f = 0; f < 2; ++f)
            qf[qg][f] = *(const bf16x8*)(Qp +
                (size_t)(i0 + wave * 32 + qg * 16 + l15) * DKc + f * 32 + quad * 8);

    f32x4 lp[2] = {(f32x4){0.f,0.f,0.f,0.f}, (f32x4){0.f,0.f,0.f,0.f}};
    f32x4 o[2][4];
#pragma unroll
    for (int qg = 0; qg < 2; ++qg)
#pragma unroll
        for (int nt = 0; nt < 4; ++nt) o[qg][nt] = (f32x4){0.f, 0.f, 0.f, 0.f};

    unsigned short* Pw = Ps + wave * 16 * 72;
    const int jmax = (i0 >> 6) + 1;                        // tiles 0..jmax

    uint4 kreg[2], vreg[2];
#pragma unroll
    for (int it = 0; it < 2; ++it) {                       // prefetch tile 0
        int r = rr + it * 32;
        kreg[it] = *(const uint4*)(Kp + (size_t)r * DKc + gg * 8);
        vreg[it] = *(const uint4*)(Vp + (size_t)r * Tc + gg * 8);
    }

    for (int jt = 0; jt <= jmax; ++jt) {
        const int j0 = jt * 64;
#pragma unroll
        for (int it = 0; it < 2; ++it) {                   // regs -> LDS
            int r = rr + it * 32;
            *(uint4*)(Ks + r * 72 + gg * 8) = kreg[it];
            *(uint4*)(Vs + r * 72 + gg * 8) = vreg[it];
        }
        __syncthreads();
        if (jt < jmax) {                                   // prefetch next tile
            const int jn = j0 + 64;
#pragma unroll
            for (int it = 0; it < 2; ++it) {
                int r = rr + it * 32;
                kreg[it] = *(const uint4*)(Kp + (size_t)(jn + r) * DKc + gg * 8);
                vreg[it] = *(const uint4*)(Vp + (size_t)r * Tc + jn + gg * 8);
            }
        }

        // K and V fragments -> registers, shared by both q-groups
        bf16x8 kf[2][4], vf[2][4];
#pragma unroll
        for (int f = 0; f < 2; ++f)
#pragma unroll
            for (int mt = 0; mt < 4; ++mt)
                kf[f][mt] = *(const bf16x8*)(Ks + (mt * 16 + l15) * 72 + f * 32 + quad * 8);
#pragma unroll
        for (int f = 0; f < 2; ++f)
#pragma unroll
            for (int nt = 0; nt < 4; ++nt)
                vf[f][nt] = *(const bf16x8*)(Vs + (nt * 16 + l15) * 72 + f * 32 + quad * 8);

        const int rel = j0 - i0;
        const bool maskit = (jt >= jmax - 1);
#pragma unroll
        for (int qg = 0; qg < 2; ++qg) {
            // S^T: rows = keys (mt*16+quad*4+reg), cols = q = l15
            f32x4 sc[4];
#pragma unroll
            for (int mt = 0; mt < 4; ++mt) sc[mt] = (f32x4){0.f, 0.f, 0.f, 0.f};
#pragma unroll
            for (int f = 0; f < 2; ++f)
#pragma unroll
                for (int mt = 0; mt < 4; ++mt)
                    sc[mt] = MFMA16(kf[f][mt], qf[qg][f], sc[mt]);

            if (maskit) {
                int qrow = wave * 32 + qg * 16 + l15;
#pragma unroll
                for (int mt = 0; mt < 4; ++mt)
#pragma unroll
                    for (int reg = 0; reg < 4; ++reg)
                        if (rel + mt * 16 + quad * 4 + reg > qrow)
                            sc[mt][reg] = -1e30f;
            }

#pragma unroll
            for (int mt = 0; mt < 4; ++mt) {
#pragma unroll
                for (int reg = 0; reg < 4; ++reg)
                    sc[mt][reg] = __expf(sc[mt][reg]);
                lp[qg] += sc[mt];
            }

            // P[q=l15][key] -> per-wave LDS rows, packed bf16
#pragma unroll
            for (int mt = 0; mt < 4; ++mt) {
                uint2 u;
                u.x = pkbf(sc[mt][0], sc[mt][1]);
                u.y = pkbf(sc[mt][2], sc[mt][3]);
                *(uint2*)(Pw + l15 * 72 + mt * 16 + quad * 4) = u;
            }

#pragma unroll
            for (int f = 0; f < 2; ++f) {
                bf16x8 pf = *(const bf16x8*)(Pw + l15 * 72 + f * 32 + quad * 8);
#pragma unroll
                for (int nt = 0; nt < 4; ++nt)
                    o[qg][nt] = MFMA16(pf, vf[f][nt], o[qg][nt]);
            }
        }
        __syncthreads();
    }

    // row sums: in-lane hsum + cross-quad; route through LDS to C-layout
#pragma unroll
    for (int qg = 0; qg < 2; ++qg) {
        float ls = lp[qg][0] + lp[qg][1] + lp[qg][2] + lp[qg][3];
        ls += __shfl_xor(ls, 16);
        ls += __shfl_xor(ls, 32);
        Linv[wave * 32 + qg * 16 + l15] = 1.0f / ls;   // quads duplicate: benign
    }

    const int b = bh / Hc, h = bh % Hc;
#pragma unroll
    for (int qg = 0; qg < 2; ++qg) {
        f32x4 li = *(const f32x4*)(Linv + wave * 32 + qg * 16 + quad * 4);
#pragma unroll
        for (int nt = 0; nt < 4; ++nt)
#pragma unroll
            for (int reg = 0; reg < 4; ++reg) {
                int t = i0 + wave * 32 + qg * 16 + quad * 4 + reg;
                attn[(size_t)(b * Tc + t) * Dc + h * 64 + nt * 16 + l15] =
                    f2bf(o[qg][nt][reg] * li[reg]);
            }
    }
}

// ---------------------------------------------------------------------------
// Proj GEMM: A[8192][768] bf16 x WpT[768][768] bf16 (+bias) -> out fp32
// Register-prefetch pipeline. grid (64, 6), 256 thr.
// ---------------------------------------------------------------------------
__global__ __launch_bounds__(256)
void proj_gemm_kernel(const unsigned short* __restrict__ A,
                      const unsigned short* __restrict__ WT,
                      const float* __restrict__ bias, float* __restrict__ out) {
    __shared__ __align__(16) unsigned short As[128 * 40];
    __shared__ __align__(16) unsigned short Bs[128 * 40];
    const int tid = threadIdx.x;
    const int wave = tid >> 6, lane = tid & 63;
    const int quad = lane >> 4, l15 = lane & 15;
    const int wr = wave >> 1, wc = wave & 1;
    const int r0 = blockIdx.x * 128, c0 = blockIdx.y * 128;
    const int rr = tid >> 2, gg = tid & 3;

    f32x4 acc[4][4];
#pragma unroll
    for (int i = 0; i < 4; ++i)
#pragma unroll
        for (int j = 0; j < 4; ++j) acc[i][j] = (f32x4){0.f, 0.f, 0.f, 0.f};

    uint4 areg[2], breg[2];
#pragma unroll
    for (int it = 0; it < 2; ++it) {
        int r = rr + it * 64;
        areg[it] = *(const uint4*)(A + (size_t)(r0 + r) * Dc + gg * 8);
        breg[it] = *(const uint4*)(WT + (size_t)(c0 + r) * Dc + gg * 8);
    }

    for (int k0 = 0; k0 < Dc; k0 += 32) {
#pragma unroll
        for (int it = 0; it < 2; ++it) {
            int r = rr + it * 64;
            *(uint4*)(As + r * 40 + gg * 8) = areg[it];
            *(uint4*)(Bs + r * 40 + gg * 8) = breg[it];
        }
        __syncthreads();
        if (k0 + 32 < Dc) {
#pragma unroll
            for (int it = 0; it < 2; ++it) {
                int r = rr + it * 64;
                areg[it] = *(const uint4*)(A + (size_t)(r0 + r) * Dc + k0 + 32 + gg * 8);
                breg[it] = *(const uint4*)(WT + (size_t)(c0 + r) * Dc + k0 + 32 + gg * 8);
            }
        }
        bf16x8 af[4], bfr[4];
#pragma unroll
        for (int mt = 0; mt < 4; ++mt)
            af[mt] = *(const bf16x8*)(As + (wr * 64 + mt * 16 + l15) * 40 + quad * 8);
#pragma unroll
        for (int nt = 0; nt < 4; ++nt)
            bfr[nt] = *(const bf16x8*)(Bs + (wc * 64 + nt * 16 + l15) * 40 + quad * 8);
#pragma unroll
        for (int mt = 0; mt < 4; ++mt)
#pragma unroll
            for (int nt = 0; nt < 4; ++nt)
                acc[mt][nt] = MFMA16(af[mt], bfr[nt], acc[mt][nt]);
        __syncthreads();
    }

    float bv[4];
#pragma unroll
    for (int nt = 0; nt < 4; ++nt) bv[nt] = bias[c0 + wc * 64 + nt * 16 + l15];
#pragma unroll
    for (int mt = 0; mt < 4; ++mt)
#pragma unroll
        for (int reg = 0; reg < 4; ++reg) {
            int gr = r0 + wr * 64 + mt * 16 + quad * 4 + reg;
#pragma unroll
            for (int nt = 0; nt < 4; ++nt) {
                int gc = c0 + wc * 64 + nt * 16 + l15;
                out[(size_t)gr * Dc + gc] = acc[mt][nt][reg] + bv[nt];
            }
        }
}

// ---------------------------------------------------------------------------
extern "C" void kernel_launch(void* const* d_in, const int* in_sizes, int n_in,
                              void* d_out, int out_size, void* d_ws, size_t ws_size,
                              hipStream_t stream) {
    const float* x      = (const float*)d_in[0];
    const float* W_qkv  = (const float*)d_in[1];
    const float* b_qkv  = (const float*)d_in[2];
    const float* W_proj = (const float*)d_in[3];
    const float* b_proj = (const float*)d_in[4];
    float* out = (float*)d_out;

    char* ws = (char*)d_ws;
    size_t off = 0;
    auto take = [&](size_t bytes) -> char* {
        char* p = ws + off;
        off += (bytes + 255) & ~(size_t)255;
        return p;
    };
    unsigned short* WqT = (unsigned short*)take((size_t)Nqkv * Dc * 2);  // [2304][768]
    unsigned short* WpT = (unsigned short*)take((size_t)Dc * Dc * 2);    // [768][768]
    unsigned short* Qb  = (unsigned short*)take((size_t)BHc * Tc * DKc * 2);
    unsigned short* Kb  = (unsigned short*)take((size_t)BHc * Tc * DKc * 2);
    unsigned short* Vb  = (unsigned short*)take((size_t)BHc * Tc * DKc * 2);
    unsigned short* Vt  = (unsigned short*)take((size_t)BHc * Tc * DKc * 2);
    unsigned short* Xb  = Vt;  // alias: Xb dead before vtrans writes Vt (same size)
    unsigned short* An  = Vb;  // alias: Vb dead once vtrans has run

    xconv_kernel<<<dim3((Mc * Dc) / (256 * 8)), dim3(256), 0, stream>>>(x, Xb);
    wtrans_kernel<<<dim3(Dc / 64, Nqkv / 64), dim3(256), 0, stream>>>(W_qkv, WqT, Dc, Nqkv);
    wtrans_kernel<<<dim3(Dc / 64, Dc / 64), dim3(256), 0, stream>>>(W_proj, WpT, Dc, Dc);
    qkv_gemm_kernel<<<dim3(Mc / 128, Nqkv / 128), dim3(256), 0, stream>>>(Xb, WqT, b_qkv, Qb, Kb, Vb);
    vtrans_kernel<<<dim3(Tc / 64, BHc), dim3(256), 0, stream>>>(Vb, Vt);
    attn_kernel<<<dim3(Tc / 128, BHc), dim3(256), 0, stream>>>(Qb, Kb, Vt, An);
    proj_gemm_kernel<<<dim3(Mc / 128, Dc / 128), dim3(256), 0, stream>>>(An, WpT, b_proj, out);
}

// Round 5
// 291.255 us; speedup vs baseline: 1.9637x; 1.9637x over previous
//
#include <hip/hip_runtime.h>
#include <hip/hip_bf16.h>
#include <cstdint>
#include <cstddef>

// ---------------------------------------------------------------------------
// CausalSelfAttention: x[2,4096,768] fp32, W_qkv[768,2304], b_qkv, W_proj[768,768], b_proj
// bf16 MFMA (16x16x32); flash attention (S^T trick, fixed-max softmax,
// 32 Q-rows/wave) with persistent blocks + atomic work queue for balance.
// NOTE (R4 post-mortem): register-prefetch of staging tiles spills (WRITE_SIZE
// 12->26 MB) — do NOT hold staging loads in VGPRs across the compute.
// ---------------------------------------------------------------------------

typedef __attribute__((ext_vector_type(8))) short bf16x8;   // 8 bf16 = 4 VGPRs
typedef __attribute__((ext_vector_type(4))) float f32x4;

#define MFMA16(a, b, c) __builtin_amdgcn_mfma_f32_16x16x32_bf16((a), (b), (c), 0, 0, 0)

static constexpr int Bc = 2, Tc = 4096, Dc = 768, Hc = 12, DKc = 64;
static constexpr int BHc = Bc * Hc;      // 24
static constexpr int Mc = Bc * Tc;       // 8192
static constexpr int Nqkv = 3 * Dc;      // 2304
static constexpr int NQBLK = Tc / 128;   // 32 Q-blocks per bh
static constexpr unsigned int NITEMS = BHc * NQBLK;  // 768 work items

__device__ __forceinline__ unsigned short f2bf(float f) {
    union { float f; unsigned int i; } c; c.f = f;
    unsigned int x = c.i;
    return (unsigned short)((x + 0x7fffu + ((x >> 16) & 1u)) >> 16); // RNE
}
__device__ __forceinline__ unsigned int pkbf(float a, float b) {
    __hip_bfloat162 h = __float22bfloat162_rn(make_float2(a, b));   // v_cvt_pk_bf16_f32
    union { __hip_bfloat162 h; unsigned int u; } c; c.h = h;
    return c.u;
}

// ---------------------------------------------------------------------------
// x fp32 -> bf16, flat copy.
// ---------------------------------------------------------------------------
__global__ __launch_bounds__(256)
void xconv_kernel(const float* __restrict__ X, unsigned short* __restrict__ Xb) {
    size_t i = ((size_t)blockIdx.x * 256 + threadIdx.x) * 8;
    float4 a = *(const float4*)(X + i);
    float4 b = *(const float4*)(X + i + 4);
    uint4 o;
    o.x = pkbf(a.x, a.y); o.y = pkbf(a.z, a.w);
    o.z = pkbf(b.x, b.y); o.w = pkbf(b.z, b.w);
    *(uint4*)(Xb + i) = o;
}

// ---------------------------------------------------------------------------
// W [K][N] fp32 -> WT [N][K] bf16.  grid (K/64, N/64), 256 thr.
// ---------------------------------------------------------------------------
__global__ __launch_bounds__(256)
void wtrans_kernel(const float* __restrict__ W, unsigned short* __restrict__ WT,
                   int K, int N) {
    __shared__ __align__(16) unsigned short tile[64 * 72];
    const int k0 = blockIdx.x * 64;
    const int n0 = blockIdx.y * 64;
    const int tid = threadIdx.x;
#pragma unroll
    for (int it = 0; it < 4; ++it) {
        int s = tid + it * 256;
        int r = s >> 4, g = s & 15;
        float4 v = *(const float4*)(W + (size_t)(k0 + r) * N + n0 + g * 4);
        ushort4 u;
        u.x = f2bf(v.x); u.y = f2bf(v.y); u.z = f2bf(v.z); u.w = f2bf(v.w);
        *(ushort4*)(tile + r * 72 + g * 4) = u;
    }
    __syncthreads();
#pragma unroll
    for (int it = 0; it < 2; ++it) {
        int s = tid + it * 256;
        int n = s >> 3, g = s & 7;
        unsigned int p0 = (unsigned int)tile[(g * 8 + 0) * 72 + n] |
                          ((unsigned int)tile[(g * 8 + 1) * 72 + n] << 16);
        unsigned int p1 = (unsigned int)tile[(g * 8 + 2) * 72 + n] |
                          ((unsigned int)tile[(g * 8 + 3) * 72 + n] << 16);
        unsigned int p2 = (unsigned int)tile[(g * 8 + 4) * 72 + n] |
                          ((unsigned int)tile[(g * 8 + 5) * 72 + n] << 16);
        unsigned int p3 = (unsigned int)tile[(g * 8 + 6) * 72 + n] |
                          ((unsigned int)tile[(g * 8 + 7) * 72 + n] << 16);
        uint4 o; o.x = p0; o.y = p1; o.z = p2; o.w = p3;
        *(uint4*)(WT + (size_t)(n0 + n) * K + k0 + g * 8) = o;
    }
}

// ---------------------------------------------------------------------------
// QKV GEMM: Xb[8192][768] bf16 x WqT[2304][768] bf16 (+bias) -> Q/K [bh][t][dk],
// V written TRANSPOSED to Vt [bh][dk][t] (fuses old vtrans kernel).
// Q part (and its bias) pre-scaled by 1/8. grid (64, 18), 256 thr.
// ---------------------------------------------------------------------------
__global__ __launch_bounds__(256)
void qkv_gemm_kernel(const unsigned short* __restrict__ Xb,
                     const unsigned short* __restrict__ WT,
                     const float* __restrict__ bias,
                     unsigned short* __restrict__ Qb, unsigned short* __restrict__ Kb,
                     unsigned short* __restrict__ Vt) {
    __shared__ __align__(16) unsigned short As[128 * 40];
    __shared__ __align__(16) unsigned short Bs[128 * 40];
    const int tid = threadIdx.x;
    const int wave = tid >> 6, lane = tid & 63;
    const int quad = lane >> 4, l15 = lane & 15;
    const int wr = wave >> 1, wc = wave & 1;
    const int r0 = blockIdx.x * 128, c0 = blockIdx.y * 128;

    f32x4 acc[4][4];
#pragma unroll
    for (int i = 0; i < 4; ++i)
#pragma unroll
        for (int j = 0; j < 4; ++j) acc[i][j] = (f32x4){0.f, 0.f, 0.f, 0.f};

    for (int k0 = 0; k0 < Dc; k0 += 32) {
#pragma unroll
        for (int it = 0; it < 2; ++it) {
            int s = tid + it * 256;
            int r = s >> 2, g = s & 3;
            *(uint4*)(As + r * 40 + g * 8) =
                *(const uint4*)(Xb + (size_t)(r0 + r) * Dc + k0 + g * 8);
            *(uint4*)(Bs + r * 40 + g * 8) =
                *(const uint4*)(WT + (size_t)(c0 + r) * Dc + k0 + g * 8);
        }
        __syncthreads();
        bf16x8 af[4], bfr[4];
#pragma unroll
        for (int mt = 0; mt < 4; ++mt)
            af[mt] = *(const bf16x8*)(As + (wr * 64 + mt * 16 + l15) * 40 + quad * 8);
#pragma unroll
        for (int nt = 0; nt < 4; ++nt)
            bfr[nt] = *(const bf16x8*)(Bs + (wc * 64 + nt * 16 + l15) * 40 + quad * 8);
#pragma unroll
        for (int mt = 0; mt < 4; ++mt)
#pragma unroll
            for (int nt = 0; nt < 4; ++nt)
                acc[mt][nt] = MFMA16(af[mt], bfr[nt], acc[mt][nt]);
        __syncthreads();
    }

    const int part = c0 / Dc;
    const int cbase = c0 - part * Dc;
    const float scale = (part == 0) ? 0.125f : 1.0f;   // fold 1/sqrt(DK) into Q
    float bv[4];
#pragma unroll
    for (int nt = 0; nt < 4; ++nt) bv[nt] = bias[c0 + wc * 64 + nt * 16 + l15];

    if (part < 2) {
        unsigned short* dstbuf = (part == 0) ? Qb : Kb;
#pragma unroll
        for (int mt = 0; mt < 4; ++mt)
#pragma unroll
            for (int reg = 0; reg < 4; ++reg) {
                int gr = r0 + wr * 64 + mt * 16 + quad * 4 + reg;
                int b = gr >> 12, t = gr & 4095;
#pragma unroll
                for (int nt = 0; nt < 4; ++nt) {
                    int cc = cbase + wc * 64 + nt * 16 + l15;
                    int h = cc >> 6, dk = cc & 63;
                    float v = (acc[mt][nt][reg] + bv[nt]) * scale;
                    dstbuf[((size_t)(b * Hc + h) * Tc + t) * DKc + dk] = f2bf(v);
                }
            }
    } else {
        // V: write transposed [bh][dk][t]
#pragma unroll
        for (int mt = 0; mt < 4; ++mt)
#pragma unroll
            for (int reg = 0; reg < 4; ++reg) {
                int gr = r0 + wr * 64 + mt * 16 + quad * 4 + reg;
                int b = gr >> 12, t = gr & 4095;
#pragma unroll
                for (int nt = 0; nt < 4; ++nt) {
                    int cc = cbase + wc * 64 + nt * 16 + l15;
                    int h = cc >> 6, dk = cc & 63;
                    float v = acc[mt][nt][reg] + bv[nt];
                    Vt[((size_t)(b * Hc + h) * DKc + dk) * Tc + t] = f2bf(v);
                }
            }
    }
}

// ---------------------------------------------------------------------------
// Flash attention: persistent blocks + atomic work queue (balance!).
// Item w -> bh = w%24, Q-block = 31 - w/24 (longest first). 768 items.
// Wave w owns 32 Q rows (two 16-row groups). Per 64-key tile: K/V staged
// global->LDS (no reg prefetch: spills), kf/vf frags loaded once and reused
// by both q-groups, P round-trips per-wave LDS, 2 barriers/tile.
// ---------------------------------------------------------------------------
__global__ __launch_bounds__(256)
void attn_kernel(const unsigned short* __restrict__ Qb,
                 const unsigned short* __restrict__ Kb,
                 const unsigned short* __restrict__ Vt,
                 unsigned short* __restrict__ attn,
                 unsigned int* __restrict__ counter) {
    __shared__ __align__(16) unsigned short Ks[64 * 72];
    __shared__ __align__(16) unsigned short Vs[64 * 72];   // [dk][key]
    __shared__ __align__(16) unsigned short Ps[4 * 16 * 72];
    __shared__ float Linv[128];
    __shared__ unsigned int s_w;
    const int tid = threadIdx.x;
    const int wave = tid >> 6, lane = tid & 63;
    const int quad = lane >> 4, l15 = lane & 15;
    const int rr = tid >> 3, gg = tid & 7;                 // staging map
    unsigned short* Pw = Ps + wave * 16 * 72;

    for (;;) {
        if (tid == 0) s_w = atomicAdd(counter, 1u);
        __syncthreads();
        const unsigned int w = s_w;
        if (w >= NITEMS) break;
        const int bh = (int)(w % (unsigned)BHc);
        const int i0 = (NQBLK - 1 - (int)(w / (unsigned)BHc)) * 128;
        const unsigned short* Qp = Qb + (size_t)bh * Tc * DKc;
        const unsigned short* Kp = Kb + (size_t)bh * Tc * DKc;
        const unsigned short* Vp = Vt + (size_t)bh * DKc * Tc;

        // Q fragments for both 16-row groups (already scaled by 1/8)
        bf16x8 qf[2][2];
#pragma unroll
        for (int qg = 0; qg < 2; ++qg)
#pragma unroll
            for (int f = 0; f < 2; ++f)
                qf[qg][f] = *(const bf16x8*)(Qp +
                    (size_t)(i0 + wave * 32 + qg * 16 + l15) * DKc + f * 32 + quad * 8);

        f32x4 lp[2] = {(f32x4){0.f,0.f,0.f,0.f}, (f32x4){0.f,0.f,0.f,0.f}};
        f32x4 o[2][4];
#pragma unroll
        for (int qg = 0; qg < 2; ++qg)
#pragma unroll
            for (int nt = 0; nt < 4; ++nt) o[qg][nt] = (f32x4){0.f, 0.f, 0.f, 0.f};

        const int jmax = (i0 >> 6) + 1;                    // tiles 0..jmax
        for (int jt = 0; jt <= jmax; ++jt) {
            const int j0 = jt * 64;
#pragma unroll
            for (int it = 0; it < 2; ++it) {               // global -> LDS staging
                int r = rr + it * 32;
                *(uint4*)(Ks + r * 72 + gg * 8) =
                    *(const uint4*)(Kp + (size_t)(j0 + r) * DKc + gg * 8);
                *(uint4*)(Vs + r * 72 + gg * 8) =
                    *(const uint4*)(Vp + (size_t)r * Tc + j0 + gg * 8);
            }
            __syncthreads();

            // K and V fragments -> registers, shared by both q-groups
            bf16x8 kf[2][4], vf[2][4];
#pragma unroll
            for (int f = 0; f < 2; ++f)
#pragma unroll
                for (int mt = 0; mt < 4; ++mt)
                    kf[f][mt] = *(const bf16x8*)(Ks + (mt * 16 + l15) * 72 + f * 32 + quad * 8);
#pragma unroll
            for (int f = 0; f < 2; ++f)
#pragma unroll
                for (int nt = 0; nt < 4; ++nt)
                    vf[f][nt] = *(const bf16x8*)(Vs + (nt * 16 + l15) * 72 + f * 32 + quad * 8);

            const int rel = j0 - i0;
            const bool maskit = (jt >= jmax - 1);
#pragma unroll
            for (int qg = 0; qg < 2; ++qg) {
                // S^T: rows = keys (mt*16+quad*4+reg), cols = q = l15
                f32x4 sc[4];
#pragma unroll
                for (int mt = 0; mt < 4; ++mt) sc[mt] = (f32x4){0.f, 0.f, 0.f, 0.f};
#pragma unroll
                for (int f = 0; f < 2; ++f)
#pragma unroll
                    for (int mt = 0; mt < 4; ++mt)
                        sc[mt] = MFMA16(kf[f][mt], qf[qg][f], sc[mt]);

                if (maskit) {
                    int qrow = wave * 32 + qg * 16 + l15;
#pragma unroll
                    for (int mt = 0; mt < 4; ++mt)
#pragma unroll
                        for (int reg = 0; reg < 4; ++reg)
                            if (rel + mt * 16 + quad * 4 + reg > qrow)
                                sc[mt][reg] = -1e30f;
                }

#pragma unroll
                for (int mt = 0; mt < 4; ++mt) {
#pragma unroll
                    for (int reg = 0; reg < 4; ++reg)
                        sc[mt][reg] = __expf(sc[mt][reg]);
                    lp[qg] += sc[mt];
                }

                // P[q=l15][key] -> per-wave LDS rows, packed bf16
#pragma unroll
                for (int mt = 0; mt < 4; ++mt) {
                    uint2 u;
                    u.x = pkbf(sc[mt][0], sc[mt][1]);
                    u.y = pkbf(sc[mt][2], sc[mt][3]);
                    *(uint2*)(Pw + l15 * 72 + mt * 16 + quad * 4) = u;
                }

#pragma unroll
                for (int f = 0; f < 2; ++f) {
                    bf16x8 pf = *(const bf16x8*)(Pw + l15 * 72 + f * 32 + quad * 8);
#pragma unroll
                    for (int nt = 0; nt < 4; ++nt)
                        o[qg][nt] = MFMA16(pf, vf[f][nt], o[qg][nt]);
                }
            }
            __syncthreads();
        }

        // row sums: in-lane hsum + cross-quad; LDS to reach C-layout
#pragma unroll
        for (int qg = 0; qg < 2; ++qg) {
            float ls = lp[qg][0] + lp[qg][1] + lp[qg][2] + lp[qg][3];
            ls += __shfl_xor(ls, 16);
            ls += __shfl_xor(ls, 32);
            Linv[wave * 32 + qg * 16 + l15] = 1.0f / ls;   // quads duplicate: benign
        }

        const int b = bh / Hc, h = bh % Hc;
#pragma unroll
        for (int qg = 0; qg < 2; ++qg) {
            f32x4 li = *(const f32x4*)(Linv + wave * 32 + qg * 16 + quad * 4);
#pragma unroll
            for (int nt = 0; nt < 4; ++nt)
#pragma unroll
                for (int reg = 0; reg < 4; ++reg) {
                    int t = i0 + wave * 32 + qg * 16 + quad * 4 + reg;
                    attn[(size_t)(b * Tc + t) * Dc + h * 64 + nt * 16 + l15] =
                        f2bf(o[qg][nt][reg] * li[reg]);
                }
        }
        __syncthreads();   // protect s_w + LDS before next fetch
    }
}

// ---------------------------------------------------------------------------
// Proj GEMM: A[8192][768] bf16 x WpT[768][768] bf16 (+bias) -> out fp32
// grid (64, 6), 256 thr.
// ---------------------------------------------------------------------------
__global__ __launch_bounds__(256)
void proj_gemm_kernel(const unsigned short* __restrict__ A,
                      const unsigned short* __restrict__ WT,
                      const float* __restrict__ bias, float* __restrict__ out) {
    __shared__ __align__(16) unsigned short As[128 * 40];
    __shared__ __align__(16) unsigned short Bs[128 * 40];
    const int tid = threadIdx.x;
    const int wave = tid >> 6, lane = tid & 63;
    const int quad = lane >> 4, l15 = lane & 15;
    const int wr = wave >> 1, wc = wave & 1;
    const int r0 = blockIdx.x * 128, c0 = blockIdx.y * 128;

    f32x4 acc[4][4];
#pragma unroll
    for (int i = 0; i < 4; ++i)
#pragma unroll
        for (int j = 0; j < 4; ++j) acc[i][j] = (f32x4){0.f, 0.f, 0.f, 0.f};

    for (int k0 = 0; k0 < Dc; k0 += 32) {
#pragma unroll
        for (int it = 0; it < 2; ++it) {
            int s = tid + it * 256;
            int r = s >> 2, g = s & 3;
            *(uint4*)(As + r * 40 + g * 8) =
                *(const uint4*)(A + (size_t)(r0 + r) * Dc + k0 + g * 8);
            *(uint4*)(Bs + r * 40 + g * 8) =
                *(const uint4*)(WT + (size_t)(c0 + r) * Dc + k0 + g * 8);
        }
        __syncthreads();
        bf16x8 af[4], bfr[4];
#pragma unroll
        for (int mt = 0; mt < 4; ++mt)
            af[mt] = *(const bf16x8*)(As + (wr * 64 + mt * 16 + l15) * 40 + quad * 8);
#pragma unroll
        for (int nt = 0; nt < 4; ++nt)
            bfr[nt] = *(const bf16x8*)(Bs + (wc * 64 + nt * 16 + l15) * 40 + quad * 8);
#pragma unroll
        for (int mt = 0; mt < 4; ++mt)
#pragma unroll
            for (int nt = 0; nt < 4; ++nt)
                acc[mt][nt] = MFMA16(af[mt], bfr[nt], acc[mt][nt]);
        __syncthreads();
    }

    float bv[4];
#pragma unroll
    for (int nt = 0; nt < 4; ++nt) bv[nt] = bias[c0 + wc * 64 + nt * 16 + l15];
#pragma unroll
    for (int mt = 0; mt < 4; ++mt)
#pragma unroll
        for (int reg = 0; reg < 4; ++reg) {
            int gr = r0 + wr * 64 + mt * 16 + quad * 4 + reg;
#pragma unroll
            for (int nt = 0; nt < 4; ++nt) {
                int gc = c0 + wc * 64 + nt * 16 + l15;
                out[(size_t)gr * Dc + gc] = acc[mt][nt][reg] + bv[nt];
            }
        }
}

// ---------------------------------------------------------------------------
extern "C" void kernel_launch(void* const* d_in, const int* in_sizes, int n_in,
                              void* d_out, int out_size, void* d_ws, size_t ws_size,
                              hipStream_t stream) {
    const float* x      = (const float*)d_in[0];
    const float* W_qkv  = (const float*)d_in[1];
    const float* b_qkv  = (const float*)d_in[2];
    const float* W_proj = (const float*)d_in[3];
    const float* b_proj = (const float*)d_in[4];
    float* out = (float*)d_out;

    char* ws = (char*)d_ws;
    size_t off = 0;
    auto take = [&](size_t bytes) -> char* {
        char* p = ws + off;
        off += (bytes + 255) & ~(size_t)255;
        return p;
    };
    unsigned int*   cnt = (unsigned int*)take(256);
    unsigned short* WqT = (unsigned short*)take((size_t)Nqkv * Dc * 2);  // [2304][768]
    unsigned short* WpT = (unsigned short*)take((size_t)Dc * Dc * 2);    // [768][768]
    unsigned short* Qb  = (unsigned short*)take((size_t)BHc * Tc * DKc * 2);
    unsigned short* Kb  = (unsigned short*)take((size_t)BHc * Tc * DKc * 2);
    unsigned short* Vt  = (unsigned short*)take((size_t)BHc * Tc * DKc * 2);
    unsigned short* Xb  = (unsigned short*)take((size_t)Mc * Dc * 2);
    unsigned short* An  = Xb;  // alias: Xb dead after qkv_gemm

    hipMemsetAsync(cnt, 0, sizeof(unsigned int), stream);
    xconv_kernel<<<dim3((Mc * Dc) / (256 * 8)), dim3(256), 0, stream>>>(x, Xb);
    wtrans_kernel<<<dim3(Dc / 64, Nqkv / 64), dim3(256), 0, stream>>>(W_qkv, WqT, Dc, Nqkv);
    wtrans_kernel<<<dim3(Dc / 64, Dc / 64), dim3(256), 0, stream>>>(W_proj, WpT, Dc, Dc);
    qkv_gemm_kernel<<<dim3(Mc / 128, Nqkv / 128), dim3(256), 0, stream>>>(Xb, WqT, b_qkv, Qb, Kb, Vt);
    attn_kernel<<<dim3(NITEMS), dim3(256), 0, stream>>>(Qb, Kb, Vt, An, cnt);
    proj_gemm_kernel<<<dim3(Mc / 128, Dc / 128), dim3(256), 0, stream>>>(An, WpT, b_proj, out);
}